// Round 1
// baseline (143.515 us; speedup 1.0000x reference)
//
#include <hip/hip_runtime.h>
#include <hip/hip_bf16.h>

#define BN 8192      // batch rows
#define MM 8199      // real rows (BN + 7 centers)
#define MP 8208      // padded to multiple of 16
#define HH 128       // feature dim
#define EE 256       // center embedding dim
#define NTILE 513    // MP / 16 j-tiles
#define JCH 32       // j-chunks (grid.y)

typedef __attribute__((ext_vector_type(8))) short short8;   // 8 bf16 = 4 VGPRs
typedef __attribute__((ext_vector_type(4))) float floatx4;

// ---- kernel A: curr_centers[c][h] = sum_e centers[c][e]*fc_w[h][e] + fc_b[h]
__global__ __launch_bounds__(64)
void centers_kernel(const float* __restrict__ centers,
                    const float* __restrict__ fc_w,
                    const float* __restrict__ fc_b,
                    float* __restrict__ curr) {
  int o = blockIdx.x;            // 0..895 = c*128 + h
  int c = o >> 7, h = o & 127;
  int lane = threadIdx.x;
  const float4* ce = (const float4*)(centers + c * EE);
  const float4* w  = (const float4*)(fc_w + h * EE);
  float4 a = ce[lane];
  float4 b = w[lane];
  float s = a.x * b.x + a.y * b.y + a.z * b.z + a.w * b.w;
#pragma unroll
  for (int m = 1; m < 64; m <<= 1) s += __shfl_xor(s, m);
  if (lane == 0) curr[o] = s + fc_b[h];
}

// ---- kernel B: rn[r] = bf16( all_reps[r] / max(||all_reps[r]||, 1e-8) ), labels_pad
__global__ __launch_bounds__(64)
void norm_kernel(const float* __restrict__ reps,
                 const float* __restrict__ curr,
                 const int* __restrict__ labels,
                 __hip_bfloat16* __restrict__ rn,
                 int* __restrict__ labp) {
  int r = blockIdx.x;            // 0..MP-1
  int lane = threadIdx.x;
  float2 v = make_float2(0.f, 0.f);
  if (r < BN)      v = ((const float2*)(reps + (size_t)r * HH))[lane];
  else if (r < MM) v = ((const float2*)(curr + (size_t)(r - BN) * HH))[lane];
  float ss = v.x * v.x + v.y * v.y;
#pragma unroll
  for (int m = 1; m < 64; m <<= 1) ss += __shfl_xor(ss, m);
  float inv = 1.0f / fmaxf(sqrtf(ss), 1e-8f);
  __hip_bfloat162 h2;
  h2.x = __float2bfloat16(v.x * inv);
  h2.y = __float2bfloat16(v.y * inv);
  ((__hip_bfloat162*)(rn + (size_t)r * HH))[lane] = h2;
  if (lane == 0) labp[r] = (r < BN) ? labels[r] : (r < MM ? r - BN : -1);
}

// ---- kernel C: per i-row, tot_i = sum_j e_ij (j!=i, j<M), pos_i = same over label match
// e_ij = exp2((cos_ij - 1) * (0.5/TEMP) * log2e)   [global-max shift cancels in ratio]
__global__ __launch_bounds__(64)
void main_kernel(const __hip_bfloat16* __restrict__ rn,
                 const int* __restrict__ labp,
                 float* __restrict__ tot,
                 float* __restrict__ pos) {
  const int lane = threadIdx.x;
  const int q = lane >> 4, col = lane & 15;
  const int ibase = blockIdx.x * 64;
  const short* rns = (const short*)rn;

  // A fragments: lane holds A[m=col][k = kk*32 + q*8 + 0..7]
  short8 afrag[4][4];
#pragma unroll
  for (int it = 0; it < 4; ++it) {
    const short8* p = (const short8*)(rns + (size_t)(ibase + it * 16 + col) * HH + q * 8);
    afrag[it][0] = p[0];
    afrag[it][1] = p[4];
    afrag[it][2] = p[8];
    afrag[it][3] = p[12];
  }
  // i-labels for C/D layout rows: row = q*4 + r
  int labi[4][4];
#pragma unroll
  for (int it = 0; it < 4; ++it)
#pragma unroll
    for (int r = 0; r < 4; ++r)
      labi[it][r] = labp[ibase + it * 16 + q * 4 + r];

  float stot[4][4] = {};
  float spos[4][4] = {};
  const float K2 = 10.30496147f;  // 0.5/0.07 * log2(e)

  for (int t = blockIdx.y; t < NTILE; t += JCH) {
    const int jb = t * 16;
    const int jg = jb + col;
    // B fragments: lane holds B[k = kk*32 + q*8 + 0..7][n=col] = rn[jb+col][k]
    const short8* bp = (const short8*)(rns + (size_t)jg * HH + q * 8);
    short8 b0 = bp[0], b1 = bp[4], b2 = bp[8], b3 = bp[12];
    const int labj = labp[jg];
    const float jvf = (jg < MM) ? 1.f : 0.f;
#pragma unroll
    for (int it = 0; it < 4; ++it) {
      floatx4 acc = {0.f, 0.f, 0.f, 0.f};
      acc = __builtin_amdgcn_mfma_f32_16x16x32_bf16(afrag[it][0], b0, acc, 0, 0, 0);
      acc = __builtin_amdgcn_mfma_f32_16x16x32_bf16(afrag[it][1], b1, acc, 0, 0, 0);
      acc = __builtin_amdgcn_mfma_f32_16x16x32_bf16(afrag[it][2], b2, acc, 0, 0, 0);
      acc = __builtin_amdgcn_mfma_f32_16x16x32_bf16(afrag[it][3], b3, acc, 0, 0, 0);
      const bool isdiag = (jb == ibase + it * 16);  // wave-uniform
#pragma unroll
      for (int r = 0; r < 4; ++r) {
        // C/D layout: row = q*4 + r, col = lane&15 → i = ibase+it*16+q*4+r, j = jb+col
        float e = exp2f(fmaf(acc[r], K2, -K2)) * jvf;
        if (isdiag && (col == q * 4 + r)) e = 0.f;   // exclude diagonal j==i
        stot[it][r] += e;
        spos[it][r] += (labj == labi[it][r]) ? e : 0.f;
      }
    }
  }

  // reduce across the 16 column-lanes (xor over low 4 lane bits)
#pragma unroll
  for (int it = 0; it < 4; ++it)
#pragma unroll
    for (int r = 0; r < 4; ++r) {
      float tt = stot[it][r], pp = spos[it][r];
#pragma unroll
      for (int m = 1; m <= 8; m <<= 1) {
        tt += __shfl_xor(tt, m);
        pp += __shfl_xor(pp, m);
      }
      if (col == 0) {
        int i = ibase + it * 16 + q * 4 + r;
        atomicAdd(&tot[i], tt);
        atomicAdd(&pos[i], pp);
      }
    }
}

// ---- kernel D: loss = sum(lv * (lv>0.3)) / (sum(lv>0.3) + eps),
//      lv = -log( (pos/tot)/(hist[lab]+eps) + eps )
__global__ __launch_bounds__(256)
void loss_kernel(const float* __restrict__ tot,
                 const float* __restrict__ pos,
                 const int* __restrict__ labels,
                 float* __restrict__ out) {
  __shared__ int hist[8];
  __shared__ float s1[256], s2[256];
  int tid = threadIdx.x;
  if (tid < 8) hist[tid] = 0;
  __syncthreads();
  for (int i = tid; i < BN; i += 256) atomicAdd(&hist[labels[i]], 1);
  __syncthreads();
  float lsum = 0.f, msum = 0.f;
  for (int i = tid; i < BN; i += 256) {
    float t = tot[i], p = pos[i];
    float c = (float)hist[labels[i]];   // = sum(pos_mask*mask) exactly
    float pr = (p / t) / (c + 1e-8f);
    float lv = -logf(pr + 1e-8f);
    if (lv > 0.3f) { lsum += lv; msum += 1.f; }
  }
  s1[tid] = lsum; s2[tid] = msum;
  __syncthreads();
  for (int st = 128; st > 0; st >>= 1) {
    if (tid < st) { s1[tid] += s1[tid + st]; s2[tid] += s2[tid + st]; }
    __syncthreads();
  }
  if (tid == 0) out[0] = s1[0] / (s2[0] + 1e-8f);
}

extern "C" void kernel_launch(void* const* d_in, const int* in_sizes, int n_in,
                              void* d_out, int out_size, void* d_ws, size_t ws_size,
                              hipStream_t stream) {
  const float* reps    = (const float*)d_in[0];  // [8192,128]
  const int*   labels  = (const int*)d_in[1];    // [8192]
  const float* centers = (const float*)d_in[2];  // [7,256]
  const float* fc_w    = (const float*)d_in[3];  // [128,256]
  const float* fc_b    = (const float*)d_in[4];  // [128]
  float* out = (float*)d_out;

  char* ws = (char*)d_ws;
  float* curr = (float*)ws;                              // 7*128*4   = 3584 B
  int* labp   = (int*)(ws + 4096);                       // 8208*4    = 32832 B
  __hip_bfloat16* rn = (__hip_bfloat16*)(ws + 40960);    // 8208*128*2 = 2101248 B
  float* tot = (float*)(ws + 40960 + 2101248);           // 8192*4
  float* pos = tot + BN;                                 // 8192*4

  hipMemsetAsync(tot, 0, 2 * BN * sizeof(float), stream);
  centers_kernel<<<896, 64, 0, stream>>>(centers, fc_w, fc_b, curr);
  norm_kernel<<<MP, 64, 0, stream>>>(reps, curr, labels, rn, labp);
  main_kernel<<<dim3(128, JCH), 64, 0, stream>>>(rn, labp, tot, pos);
  loss_kernel<<<1, 256, 0, stream>>>(tot, pos, labels, out);
}